// Round 13
// baseline (950.877 us; speedup 1.0000x reference)
//
#include <hip/hip_runtime.h>
#include <hip/hip_bf16.h>

#define B_   256
#define T_   512
#define H_   128
#define G3_  384

// ---- tiled GEMM config ----
#define TM   128
#define TN   128
#define TK   32
#define LDA  132

// log2(e) and 2*log2(e): gate pre-activations are pre-scaled so the serial
// recurrence uses raw v_exp_f32 (2^x) with no per-call *1.4427 mul.
#define LOG2E_F  1.4426950408889634f
#define LOG2E2_F 2.8853900817779268f

typedef float v4f __attribute__((ext_vector_type(4)));
typedef float v2f __attribute__((ext_vector_type(2)));

__device__ __forceinline__ float fast_rcp(float x) {
    return __builtin_amdgcn_rcpf(x);
}
__device__ __forceinline__ float exp2_raw(float x) {
    return __builtin_amdgcn_exp2f(x);   // v_exp_f32: 2^x
}

// Packed FMA, all operands arch-VGPR (R15-proven; VOP3P cannot take AGPR
// sources on gfx950 — R17 compile falsifier). The "v" constraints also
// force W out of AGPRs at every use (kills the copy ghost).
__device__ __forceinline__ void pk_fma(v2f& acc, v2f a, v2f b) {
    asm("v_pk_fma_f32 %0, %1, %2, %0" : "+v"(acc) : "v"(a), "v"(b));
}

// Butterfly sum over each aligned 4-lane quad, pure DPP, result on ALL lanes.
__device__ __forceinline__ float bfly_fold4(float v) {
    int x;
    x = __builtin_amdgcn_update_dpp(0, __float_as_int(v), 0x0B1, 0xF, 0xF, true);
    v += __int_as_float(x);   // xor 1
    x = __builtin_amdgcn_update_dpp(0, __float_as_int(v), 0x04E, 0xF, 0xF, true);
    v += __int_as_float(x);   // xor 2
    return v;
}

// Butterfly sum over each aligned 8-lane group (R8/R18-proven), all lanes.
__device__ __forceinline__ float bfly_fold8(float v) {
    int x;
    x = __builtin_amdgcn_update_dpp(0, __float_as_int(v), 0x0B1, 0xF, 0xF, true);
    v += __int_as_float(x);   // xor 1
    x = __builtin_amdgcn_update_dpp(0, __float_as_int(v), 0x04E, 0xF, 0xF, true);
    v += __int_as_float(x);   // xor 2
    x = __builtin_amdgcn_update_dpp(0, __float_as_int(v), 0x141, 0xF, 0xF, true);
    v += __int_as_float(x);   // half mirror within the 8-group
    return v;
}

// R19 relaxed barrier (measured neutral vs __syncthreads, absmax 0): drains
// lgkmcnt only — global prefetch loads keep their compiler vmcnt waits at
// point of use; hseq stores drain at kernel end.
__device__ __forceinline__ void lds_barrier() {
    asm volatile("s_waitcnt lgkmcnt(0)" ::: "memory");
    __builtin_amdgcn_s_barrier();
    asm volatile("" ::: "memory");
}

// ---------------------------------------------------------------------------
// gx GEMM (R2 structure; R14 bias2 fold; R15 exp2 pre-scale epilogue)
// ---------------------------------------------------------------------------
template<bool GATHER>
__global__ __launch_bounds__(256, 2)
void gx_gemm(const float* __restrict__ X,
             const int*   __restrict__ idx,
             const float* __restrict__ emb,
             const float* __restrict__ W,     // [384,128] row-major
             const float* __restrict__ bias,  // [384]  (b_ih)
             const float* __restrict__ bias2, // [384]  (b_hh; only n<256 used)
             float*       __restrict__ gx)    // [M,384]
{
    __shared__ __align__(16) float As[2][TK][LDA];
    __shared__ __align__(16) float Bs[2][TK][LDA];

    const int tid = threadIdx.x;
    const int tn  = tid & 15;
    const int tm  = tid >> 4;
    const int n0  = blockIdx.x * TN;
    const int m0  = blockIdx.y * TM;

    const int q  = tid & 7;
    const float* rowA[4];
    const float* rowB[4];
#pragma unroll
    for (int s = 0; s < 4; s++) {
        const int r = (tid >> 3) + 32 * s;
        rowA[s] = GATHER ? (emb + (size_t)idx[m0 + r] * H_)
                         : (X + (size_t)(m0 + r) * H_);
        rowB[s] = W + (size_t)(n0 + r) * H_;
    }

    float4 stA[4], stB[4];
    auto load_chunk = [&](int kc) {
#pragma unroll
        for (int s = 0; s < 4; s++) {
            stA[s] = *(const float4*)(rowA[s] + kc + q * 4);
            stB[s] = *(const float4*)(rowB[s] + kc + q * 4);
        }
    };
    auto store_chunk = [&](int buf) {
#pragma unroll
        for (int s = 0; s < 4; s++) {
            const int r = (tid >> 3) + 32 * s;
#pragma unroll
            for (int d = 0; d < 4; d++) {
                As[buf][q * 4 + d][r] = ((const float*)&stA[s])[d];
                Bs[buf][q * 4 + d][r] = ((const float*)&stB[s])[d];
            }
        }
    };

    float4 acc[2][2][4];
#pragma unroll
    for (int a = 0; a < 2; a++)
#pragma unroll
        for (int b = 0; b < 2; b++)
#pragma unroll
            for (int c = 0; c < 4; c++) acc[a][b][c] = make_float4(0.f, 0.f, 0.f, 0.f);

    load_chunk(0);
    store_chunk(0);
    __syncthreads();

    for (int c = 0; c < 4; c++) {
        if (c < 3) load_chunk((c + 1) * TK);
        const int buf = c & 1;
#pragma unroll 4
        for (int k = 0; k < TK; k++) {
            float4 a0 = *(const float4*)&As[buf][k][tm * 4];
            float4 a1 = *(const float4*)&As[buf][k][64 + tm * 4];
            float4 b0 = *(const float4*)&Bs[buf][k][tn * 4];
            float4 b1 = *(const float4*)&Bs[buf][k][64 + tn * 4];
            float4 av[2] = {a0, a1}, bv[2] = {b0, b1};
#pragma unroll
            for (int mg = 0; mg < 2; mg++)
#pragma unroll
                for (int mi = 0; mi < 4; mi++) {
                    const float am = ((const float*)&av[mg])[mi];
#pragma unroll
                    for (int ng = 0; ng < 2; ng++) {
                        acc[mg][ng][mi].x = fmaf(am, bv[ng].x, acc[mg][ng][mi].x);
                        acc[mg][ng][mi].y = fmaf(am, bv[ng].y, acc[mg][ng][mi].y);
                        acc[mg][ng][mi].z = fmaf(am, bv[ng].z, acc[mg][ng][mi].z);
                        acc[mg][ng][mi].w = fmaf(am, bv[ng].w, acc[mg][ng][mi].w);
                    }
                }
        }
        if (c < 3) {
            store_chunk(buf ^ 1);
            __syncthreads();
        }
    }

    float4 bb0 = *(const float4*)(bias + n0 + tn * 4);
    float4 bb1 = *(const float4*)(bias + n0 + 64 + tn * 4);
    if (n0 < 2 * H_) {   // r/z gate regions: fold hidden bias in here (uniform)
        const float4 c0 = *(const float4*)(bias2 + n0 + tn * 4);
        const float4 c1 = *(const float4*)(bias2 + n0 + 64 + tn * 4);
        bb0.x += c0.x; bb0.y += c0.y; bb0.z += c0.z; bb0.w += c0.w;
        bb1.x += c1.x; bb1.y += c1.y; bb1.z += c1.z; bb1.w += c1.w;
    }
    // exp2 pre-scale (uniform per block: r,z -> log2e; n -> 2log2e)
    const float esc = (n0 < 2 * H_) ? LOG2E_F : LOG2E2_F;
#pragma unroll
    for (int mg = 0; mg < 2; mg++)
#pragma unroll
        for (int mi = 0; mi < 4; mi++) {
            const int m = m0 + mg * 64 + tm * 4 + mi;
            float* dst = gx + (size_t)m * G3_ + n0;
            float4 v0 = acc[mg][0][mi];
            v0.x = (v0.x + bb0.x) * esc; v0.y = (v0.y + bb0.y) * esc;
            v0.z = (v0.z + bb0.z) * esc; v0.w = (v0.w + bb0.w) * esc;
            float4 v1 = acc[mg][1][mi];
            v1.x = (v1.x + bb1.x) * esc; v1.y = (v1.y + bb1.y) * esc;
            v1.z = (v1.z + bb1.z) * esc; v1.w = (v1.w + bb1.w) * esc;
            *(float4*)(dst + tn * 4) = v0;
            *(float4*)(dst + 64 + tn * 4) = v1;
        }
}

// ---------------------------------------------------------------------------
// GRU recurrence K=8, 1024 thr, 4 waves/SIMD — R20 (= R16 with both faults
// fixed). Layer-1 A/B experiment.
//
// R19 closed the stall ledger: 565 cyc/step of pure latency (post-barrier
// ds_read ~120cyc + DPP folds + exp2/rcp chain) that 2 lockstep waves/SIMD
// cannot hide. This kernel doubles TLP to 4 waves/SIMD. R16's two faults:
//  (a) rotation f=(c+ks)&3 had period 4 -> ks/ks+4 bank-collide (3.4e7
//      conflicts). Fixed with rot=ks>>1 (R13/R18-measured 0-conflict form):
//      slot-c quad = 4*(ks&1) + ((c+rot)&3) — bijective over 8 quads.
//  (b) plain-C dots let the allocator AGPR-park W (VGPR=52). Fixed with the
//      R18 forced-"v" pk_fma body; W = 24 v2f (48 regs) + live ~45 fits the
//      128-reg budget of waves_per_eu(4,4).
//
// Thread (jg = tid>>3, ks = tid&7) owns unit jg, cols ks*16..+15.
// Writes (ks==0): 8 writers/wave at consecutive words jg — conflict-free.
// ---------------------------------------------------------------------------
template<bool STORE_H, bool FINAL>
__global__ __launch_bounds__(1024)
__attribute__((amdgpu_waves_per_eu(4, 4)))
void gru_recD(const float* __restrict__ gx,   // [B,T,384] pre-scaled, r/z incl b_hh
              const float* __restrict__ Whh,  // [384,128]
              const float* __restrict__ bhh,  // [384]
              float*       __restrict__ hseq, // [B,T,128] if STORE_H
              const float* __restrict__ fc_w, // [3,128]  if FINAL
              const float* __restrict__ fc_b, // [3]      if FINAL
              float*       __restrict__ out)  // [B,3]    if FINAL
{
    __shared__ __align__(16) float h2[2][H_];   // double-buffered h (LINEAR)

    const int tid = threadIdx.x;
    const int b   = blockIdx.x;
    const int jg  = tid >> 3;      // hidden unit 0..127
    const int ks  = tid & 7;       // k-slice 0..7 (16 cols each)
    const int rot = ks >> 1;       // bank-de-alias rotation (R13/R18 form)

    // --- W fragment: rows jg/jg+128/jg+256, cols ks*16..+15, chunks in
    // rotated order, pre-scaled for exp2 gate forms. 24 v2f = 48 regs. ---
    v2f Wr[8], Wz[8], Wn[8];
    {
        const float* r0 = Whh + (size_t)(jg      ) * H_ + ks * 16;
        const float* z0 = Whh + (size_t)(jg + 128) * H_ + ks * 16;
        const float* n0 = Whh + (size_t)(jg + 256) * H_ + ks * 16;
#pragma unroll
        for (int c = 0; c < 4; c++) {
            const int f = ((c + rot) & 3) * 4;
            v4f t;
            t = *(const v4f*)(r0 + f) * LOG2E_F;
            Wr[2 * c] = t.lo; Wr[2 * c + 1] = t.hi;
            t = *(const v4f*)(z0 + f) * LOG2E_F;
            Wz[2 * c] = t.lo; Wz[2 * c + 1] = t.hi;
            t = *(const v4f*)(n0 + f) * LOG2E2_F;
            Wn[2 * c] = t.lo; Wn[2 * c + 1] = t.hi;
        }
    }

    const float bhn = bhh[jg + 2 * H_] * LOG2E2_F;  // r,z biases folded into gx

    const float* gxb = gx + (size_t)b * T_ * G3_;
    float gr = gxb[jg], gz = gxb[jg + H_], gn = gxb[jg + 2 * H_];
    float h_old = 0.0f;

    if (tid < H_) h2[0][tid] = 0.0f;

    // rotated read offsets (words) into the linear 128-float h buffer
    const int ho0 = ks * 16 + (((0 + rot) & 3) << 2);
    const int ho1 = ks * 16 + (((1 + rot) & 3) << 2);
    const int ho2 = ks * 16 + (((2 + rot) & 3) << 2);
    const int ho3 = ks * 16 + (((3 + rot) & 3) << 2);

    const float* gnx = gxb + G3_;
    float* hp = STORE_H ? (hseq + (size_t)b * T_ * H_ + jg) : nullptr;

    __syncthreads();

#define GRU_STEPD(HIN, HOUT)                                                  \
    {                                                                         \
        const float gr2_ = gnx[jg];                                           \
        const float gz2_ = gnx[jg + H_];                                      \
        const float gn2_ = gnx[jg + 2 * H_];                                  \
        gnx += G3_;                                                           \
        v2f pr = {0.f, 0.f}, pz = {0.f, 0.f}, pn = {0.f, 0.f};                \
        {                                                                     \
            v4f hv; v2f hlo, hhi;                                             \
            hv = *(const v4f*)&(HIN)[ho0]; hlo = hv.lo; hhi = hv.hi;          \
            pk_fma(pr, hlo, Wr[0]); pk_fma(pr, hhi, Wr[1]);                   \
            pk_fma(pz, hlo, Wz[0]); pk_fma(pz, hhi, Wz[1]);                   \
            pk_fma(pn, hlo, Wn[0]); pk_fma(pn, hhi, Wn[1]);                   \
            hv = *(const v4f*)&(HIN)[ho1]; hlo = hv.lo; hhi = hv.hi;          \
            pk_fma(pr, hlo, Wr[2]); pk_fma(pr, hhi, Wr[3]);                   \
            pk_fma(pz, hlo, Wz[2]); pk_fma(pz, hhi, Wz[3]);                   \
            pk_fma(pn, hlo, Wn[2]); pk_fma(pn, hhi, Wn[3]);                   \
            hv = *(const v4f*)&(HIN)[ho2]; hlo = hv.lo; hhi = hv.hi;          \
            pk_fma(pr, hlo, Wr[4]); pk_fma(pr, hhi, Wr[5]);                   \
            pk_fma(pz, hlo, Wz[4]); pk_fma(pz, hhi, Wz[5]);                   \
            pk_fma(pn, hlo, Wn[4]); pk_fma(pn, hhi, Wn[5]);                   \
            hv = *(const v4f*)&(HIN)[ho3]; hlo = hv.lo; hhi = hv.hi;          \
            pk_fma(pr, hlo, Wr[6]); pk_fma(pr, hhi, Wr[7]);                   \
            pk_fma(pz, hlo, Wz[6]); pk_fma(pz, hhi, Wz[7]);                   \
            pk_fma(pn, hlo, Wn[6]); pk_fma(pn, hhi, Wn[7]);                   \
        }                                                                     \
        const float p0 = bfly_fold8(pr.x + pr.y);                             \
        const float p1 = bfly_fold8(pz.x + pz.y);                             \
        const float p2 = bfly_fold8(pn.x + pn.y);                             \
        const float r_ = fast_rcp(1.0f + exp2_raw(-(gr + p0)));               \
        const float z_ = fast_rcp(1.0f + exp2_raw(-(gz + p1)));               \
        const float n_ = fmaf(-2.0f,                                          \
            fast_rcp(exp2_raw(gn + r_ * (p2 + bhn)) + 1.0f), 1.0f);           \
        h_old = fmaf(z_, h_old - n_, n_);                                     \
        if (ks == 0) {                                                        \
            (HOUT)[jg] = h_old;                                               \
            if (STORE_H) *hp = h_old;                                         \
        }                                                                     \
        if (STORE_H) hp += H_;                                                \
        gr = gr2_; gz = gz2_; gn = gn2_;                                      \
        lds_barrier();                                                        \
    }

    for (int t = 0; t < T_; t += 2) {
        GRU_STEPD(h2[0], h2[1])
        GRU_STEPD(h2[1], h2[0])
    }
#undef GRU_STEPD

    if (FINAL) {
        if (ks == 0) h2[1][jg] = fmaxf(h_old, 0.0f);
        __syncthreads();
        if (tid < 3) {
            float acc = fc_b[tid];
            const float* fw = fc_w + tid * H_;
#pragma unroll
            for (int k = 0; k < H_; k++) acc = fmaf(h2[1][k], fw[k], acc);
            out[b * 3 + tid] = acc;
        }
    }
}

// ---------------------------------------------------------------------------
// GRU recurrence K=4 — R15 kernel, UNCHANGED (A/B control, runs layer 2).
// ---------------------------------------------------------------------------
template<bool STORE_H, bool FINAL>
__global__ __launch_bounds__(512)
__attribute__((amdgpu_waves_per_eu(2, 2)))
void gru_rec(const float* __restrict__ gx,   // [B,T,384] pre-scaled, r/z incl b_hh
             const float* __restrict__ Whh,  // [384,128]
             const float* __restrict__ bhh,  // [384]
             float*       __restrict__ hseq, // [B,T,128] if STORE_H
             const float* __restrict__ fc_w, // [3,128]  if FINAL
             const float* __restrict__ fc_b, // [3]      if FINAL
             float*       __restrict__ out)  // [B,3]    if FINAL
{
    __shared__ __align__(16) float h2[2][H_];   // double-buffered swizzled h

    const int tid = threadIdx.x;
    const int b   = blockIdx.x;
    const int jg  = tid >> 2;      // hidden unit 0..127
    const int ks  = tid & 3;       // k-slice 0..3 (32 cols each)

    v2f Wr[16], Wz[16], Wn[16];
    {
        const v4f* wr = (const v4f*)(Whh + (size_t)(jg      ) * H_ + ks * 32);
        const v4f* wz = (const v4f*)(Whh + (size_t)(jg + 128) * H_ + ks * 32);
        const v4f* wn = (const v4f*)(Whh + (size_t)(jg + 256) * H_ + ks * 32);
#pragma unroll
        for (int c = 0; c < 8; c++) {
            v4f t;
            t = wr[c] * LOG2E_F;  Wr[2 * c] = t.lo; Wr[2 * c + 1] = t.hi;
            t = wz[c] * LOG2E_F;  Wz[2 * c] = t.lo; Wz[2 * c + 1] = t.hi;
            t = wn[c] * LOG2E2_F; Wn[2 * c] = t.lo; Wn[2 * c + 1] = t.hi;
        }
    }

    const float bhn = bhh[jg + 2 * H_] * LOG2E2_F;

    const float* gxb = gx + (size_t)b * T_ * G3_;
    float gr = gxb[jg], gz = gxb[jg + 128], gn = gxb[jg + 256];
    float h_old = 0.0f;

    if (tid < H_) h2[0][tid] = 0.0f;

    const int hw = ((jg >> 2) & 7) * 16 + (jg >> 5) * 4 + (jg & 3);
    const int hb = ks * 4;

    const float* gnx = gxb + G3_;
    float* hp = STORE_H ? (hseq + (size_t)b * T_ * H_ + jg) : nullptr;

    __syncthreads();

#define GRU_STEP(HIN, HOUT)                                                   \
    {                                                                         \
        const float gr2_ = gnx[jg];                                           \
        const float gz2_ = gnx[jg + 128];                                     \
        const float gn2_ = gnx[jg + 256];                                     \
        gnx += G3_;                                                           \
        v2f pr = {0.f, 0.f}, pz = {0.f, 0.f}, pn = {0.f, 0.f};                \
        _Pragma("unroll")                                                     \
        for (int c = 0; c < 8; c++) {                                         \
            v4f hv = *(const v4f*)&(HIN)[16 * c + hb];                        \
            v2f hlo = hv.lo, hhi = hv.hi;                                     \
            pk_fma(pr, hlo, Wr[2 * c]);  pk_fma(pr, hhi, Wr[2 * c + 1]);      \
            pk_fma(pz, hlo, Wz[2 * c]);  pk_fma(pz, hhi, Wz[2 * c + 1]);      \
            pk_fma(pn, hlo, Wn[2 * c]);  pk_fma(pn, hhi, Wn[2 * c + 1]);      \
        }                                                                     \
        const float p0 = bfly_fold4(pr.x + pr.y);                             \
        const float p1 = bfly_fold4(pz.x + pz.y);                             \
        const float p2 = bfly_fold4(pn.x + pn.y);                             \
        const float r_ = fast_rcp(1.0f + exp2_raw(-(gr + p0)));               \
        const float z_ = fast_rcp(1.0f + exp2_raw(-(gz + p1)));               \
        const float n_ = fmaf(-2.0f,                                          \
            fast_rcp(exp2_raw(gn + r_ * (p2 + bhn)) + 1.0f), 1.0f);           \
        h_old = fmaf(z_, h_old - n_, n_);                                     \
        if (ks == 0) {                                                        \
            (HOUT)[hw] = h_old;                                               \
            if (STORE_H) *hp = h_old;                                         \
        }                                                                     \
        if (STORE_H) hp += H_;                                                \
        gr = gr2_; gz = gz2_; gn = gn2_;                                      \
        __syncthreads();                                                      \
    }

    for (int t = 0; t < T_; t += 2) {
        GRU_STEP(h2[0], h2[1])
        GRU_STEP(h2[1], h2[0])
    }
#undef GRU_STEP

    if (FINAL) {
        if (ks == 0) h2[1][jg] = fmaxf(h_old, 0.0f);
        __syncthreads();
        if (tid < 3) {
            float acc = fc_b[tid];
            const float* fw = fc_w + tid * H_;
#pragma unroll
            for (int k = 0; k < H_; k++) acc = fmaf(h2[1][k], fw[k], acc);
            out[b * 3 + tid] = acc;
        }
    }
}

// ---------------------------------------------------------------------------
extern "C" void kernel_launch(void* const* d_in, const int* in_sizes, int n_in,
                              void* d_out, int out_size, void* d_ws, size_t ws_size,
                              hipStream_t stream)
{
    const int*   x    = (const int*)  d_in[0];
    const float* emb  = (const float*)d_in[1];
    const float* W_ih = (const float*)d_in[2];  // [2,384,128]
    const float* W_hh = (const float*)d_in[3];  // [2,384,128]
    const float* b_ih = (const float*)d_in[4];  // [2,384]
    const float* b_hh = (const float*)d_in[5];  // [2,384]
    const float* fc_w = (const float*)d_in[6];  // [3,128]
    const float* fc_b = (const float*)d_in[7];  // [3]
    float* out = (float*)d_out;

    const int M = B_ * T_;                                   // 131072 rows
    const size_t gx_f32 = (size_t)M * G3_ * sizeof(float);   // 201.3 MB

    float* gx = (float*)d_ws;
    float* h1 = (float*)((char*)d_ws + gx_f32);              // 67.1 MB

    dim3 ggx(G3_ / TN, M / TM);   // (3, 1024)
    dim3 bgx(256);
    dim3 grec(B_);

    hipLaunchKernelGGL((gx_gemm<true>), ggx, bgx, 0, stream,
                       nullptr, x, emb, W_ih, b_ih, b_hh, gx);
    // A/B: layer 1 = K=8 / 1024 thr / 4 waves-per-SIMD (R16 faults fixed)
    hipLaunchKernelGGL((gru_recD<true, false>), grec, dim3(1024), 0, stream,
                       gx, W_hh, b_hh, h1, nullptr, nullptr, nullptr);
    hipLaunchKernelGGL((gx_gemm<false>), ggx, bgx, 0, stream,
                       h1, nullptr, nullptr, W_ih + G3_ * H_, b_ih + G3_,
                       b_hh + G3_, gx);
    // control: layer 2 = R15 K=4 kernel unchanged
    hipLaunchKernelGGL((gru_rec<false, true>), grec, dim3(512), 0, stream,
                       gx, W_hh + G3_ * H_, b_hh + G3_, nullptr, fc_w, fc_b, out);
}

// Round 14
// 882.224 us; speedup vs baseline: 1.0778x; 1.0778x over previous
//
#include <hip/hip_runtime.h>
#include <hip/hip_bf16.h>

#define B_   256
#define T_   512
#define H_   128
#define G3_  384

// ---- tiled GEMM config ----
#define TM   128
#define TN   128
#define TK   32
#define LDA  132

// log2(e) and 2*log2(e): gate pre-activations are pre-scaled so the serial
// recurrence uses raw v_exp_f32 (2^x) with no per-call *1.4427 mul.
#define LOG2E_F  1.4426950408889634f
#define LOG2E2_F 2.8853900817779268f

typedef float v4f __attribute__((ext_vector_type(4)));
typedef float v2f __attribute__((ext_vector_type(2)));

__device__ __forceinline__ float fast_rcp(float x) {
    return __builtin_amdgcn_rcpf(x);
}
__device__ __forceinline__ float exp2_raw(float x) {
    return __builtin_amdgcn_exp2f(x);   // v_exp_f32: 2^x
}

// Packed FMA (R15-proven best dot form). Ledger note (R20 post-mortem):
// VOP3P pk_fma_f32 is HALF-RATE (4 cyc/wave64) — 48 pk = 96 fmac in cost.
// Its win over scalar (R14 294 -> R15 274) is scheduling, not rate.
__device__ __forceinline__ void pk_fma(v2f& acc, v2f a, v2f b) {
    asm("v_pk_fma_f32 %0, %1, %2, %0" : "+v"(acc) : "v"(a), "v"(b));
}

// Butterfly sum over each aligned 4-lane quad, pure DPP, result on ALL lanes.
__device__ __forceinline__ float bfly_fold4(float v) {
    int x;
    x = __builtin_amdgcn_update_dpp(0, __float_as_int(v), 0x0B1, 0xF, 0xF, true);
    v += __int_as_float(x);   // xor 1
    x = __builtin_amdgcn_update_dpp(0, __float_as_int(v), 0x04E, 0xF, 0xF, true);
    v += __int_as_float(x);   // xor 2
    return v;
}

// R19 relaxed barrier (measured equal to __syncthreads, absmax 0): drains
// lgkmcnt only — global prefetch loads keep their compiler vmcnt waits at
// point of use; hseq stores drain at kernel end.
__device__ __forceinline__ void lds_barrier() {
    asm volatile("s_waitcnt lgkmcnt(0)" ::: "memory");
    __builtin_amdgcn_s_barrier();
    asm volatile("" ::: "memory");
}

// ---------------------------------------------------------------------------
// gx GEMM (R2 structure; R14 bias2 fold; R15 exp2 pre-scale epilogue)
// ---------------------------------------------------------------------------
template<bool GATHER>
__global__ __launch_bounds__(256, 2)
void gx_gemm(const float* __restrict__ X,
             const int*   __restrict__ idx,
             const float* __restrict__ emb,
             const float* __restrict__ W,     // [384,128] row-major
             const float* __restrict__ bias,  // [384]  (b_ih)
             const float* __restrict__ bias2, // [384]  (b_hh; only n<256 used)
             float*       __restrict__ gx)    // [M,384]
{
    __shared__ __align__(16) float As[2][TK][LDA];
    __shared__ __align__(16) float Bs[2][TK][LDA];

    const int tid = threadIdx.x;
    const int tn  = tid & 15;
    const int tm  = tid >> 4;
    const int n0  = blockIdx.x * TN;
    const int m0  = blockIdx.y * TM;

    const int q  = tid & 7;
    const float* rowA[4];
    const float* rowB[4];
#pragma unroll
    for (int s = 0; s < 4; s++) {
        const int r = (tid >> 3) + 32 * s;
        rowA[s] = GATHER ? (emb + (size_t)idx[m0 + r] * H_)
                         : (X + (size_t)(m0 + r) * H_);
        rowB[s] = W + (size_t)(n0 + r) * H_;
    }

    float4 stA[4], stB[4];
    auto load_chunk = [&](int kc) {
#pragma unroll
        for (int s = 0; s < 4; s++) {
            stA[s] = *(const float4*)(rowA[s] + kc + q * 4);
            stB[s] = *(const float4*)(rowB[s] + kc + q * 4);
        }
    };
    auto store_chunk = [&](int buf) {
#pragma unroll
        for (int s = 0; s < 4; s++) {
            const int r = (tid >> 3) + 32 * s;
#pragma unroll
            for (int d = 0; d < 4; d++) {
                As[buf][q * 4 + d][r] = ((const float*)&stA[s])[d];
                Bs[buf][q * 4 + d][r] = ((const float*)&stB[s])[d];
            }
        }
    };

    float4 acc[2][2][4];
#pragma unroll
    for (int a = 0; a < 2; a++)
#pragma unroll
        for (int b = 0; b < 2; b++)
#pragma unroll
            for (int c = 0; c < 4; c++) acc[a][b][c] = make_float4(0.f, 0.f, 0.f, 0.f);

    load_chunk(0);
    store_chunk(0);
    __syncthreads();

    for (int c = 0; c < 4; c++) {
        if (c < 3) load_chunk((c + 1) * TK);
        const int buf = c & 1;
#pragma unroll 4
        for (int k = 0; k < TK; k++) {
            float4 a0 = *(const float4*)&As[buf][k][tm * 4];
            float4 a1 = *(const float4*)&As[buf][k][64 + tm * 4];
            float4 b0 = *(const float4*)&Bs[buf][k][tn * 4];
            float4 b1 = *(const float4*)&Bs[buf][k][64 + tn * 4];
            float4 av[2] = {a0, a1}, bv[2] = {b0, b1};
#pragma unroll
            for (int mg = 0; mg < 2; mg++)
#pragma unroll
                for (int mi = 0; mi < 4; mi++) {
                    const float am = ((const float*)&av[mg])[mi];
#pragma unroll
                    for (int ng = 0; ng < 2; ng++) {
                        acc[mg][ng][mi].x = fmaf(am, bv[ng].x, acc[mg][ng][mi].x);
                        acc[mg][ng][mi].y = fmaf(am, bv[ng].y, acc[mg][ng][mi].y);
                        acc[mg][ng][mi].z = fmaf(am, bv[ng].z, acc[mg][ng][mi].z);
                        acc[mg][ng][mi].w = fmaf(am, bv[ng].w, acc[mg][ng][mi].w);
                    }
                }
        }
        if (c < 3) {
            store_chunk(buf ^ 1);
            __syncthreads();
        }
    }

    float4 bb0 = *(const float4*)(bias + n0 + tn * 4);
    float4 bb1 = *(const float4*)(bias + n0 + 64 + tn * 4);
    if (n0 < 2 * H_) {   // r/z gate regions: fold hidden bias in here (uniform)
        const float4 c0 = *(const float4*)(bias2 + n0 + tn * 4);
        const float4 c1 = *(const float4*)(bias2 + n0 + 64 + tn * 4);
        bb0.x += c0.x; bb0.y += c0.y; bb0.z += c0.z; bb0.w += c0.w;
        bb1.x += c1.x; bb1.y += c1.y; bb1.z += c1.z; bb1.w += c1.w;
    }
    // exp2 pre-scale (uniform per block: r,z -> log2e; n -> 2log2e)
    const float esc = (n0 < 2 * H_) ? LOG2E_F : LOG2E2_F;
#pragma unroll
    for (int mg = 0; mg < 2; mg++)
#pragma unroll
        for (int mi = 0; mi < 4; mi++) {
            const int m = m0 + mg * 64 + tm * 4 + mi;
            float* dst = gx + (size_t)m * G3_ + n0;
            float4 v0 = acc[mg][0][mi];
            v0.x = (v0.x + bb0.x) * esc; v0.y = (v0.y + bb0.y) * esc;
            v0.z = (v0.z + bb0.z) * esc; v0.w = (v0.w + bb0.w) * esc;
            float4 v1 = acc[mg][1][mi];
            v1.x = (v1.x + bb1.x) * esc; v1.y = (v1.y + bb1.y) * esc;
            v1.z = (v1.z + bb1.z) * esc; v1.w = (v1.w + bb1.w) * esc;
            *(float4*)(dst + tn * 4) = v0;
            *(float4*)(dst + 64 + tn * 4) = v1;
        }
}

// ---------------------------------------------------------------------------
// GRU recurrence — R21 = R15 configuration restored for BOTH layers (the
// session-best 826us run), with the R19 lds_barrier (measured equal).
//
// Final ledger (R12-R20 experiments): step = 1284 cyc = 708 issue + ~575
// latency. Issue decomposition per wave (matches VALUBusy to 2%):
//   48 half-rate pk_fma (192) + 6 quarter-rate trans (48) + DPP folds (24)
//   + ~45 scalar VALU (90) = 354 cyc x 2 waves/SIMD.
// Falsified levers: LDS bandwidth (R18: halving traffic regressed), barrier
// vmcnt drain (R19: null), AGPR copies (R12 run: 128-reg variant == 88-reg
// variant), 4-wave TLP (R16/R20: K=8 redundancy inflates issue +47%).
//
// Thread (jg = tid>>2, ks = tid&3) owns unit jg, cols ks*32..+31.
// h2 swizzle: h[j] at word sw(j)=16*((j>>2)&7)+4*(j>>5)+(j&3); reads at
// 16c+4ks -> 4 distinct bank quads x 16-lane broadcast (measured 0 confl).
// ---------------------------------------------------------------------------
template<bool STORE_H, bool FINAL>
__global__ __launch_bounds__(512)
__attribute__((amdgpu_waves_per_eu(2, 2)))
void gru_rec(const float* __restrict__ gx,   // [B,T,384] pre-scaled, r/z incl b_hh
             const float* __restrict__ Whh,  // [384,128]
             const float* __restrict__ bhh,  // [384]
             float*       __restrict__ hseq, // [B,T,128] if STORE_H
             const float* __restrict__ fc_w, // [3,128]  if FINAL
             const float* __restrict__ fc_b, // [3]      if FINAL
             float*       __restrict__ out)  // [B,3]    if FINAL
{
    __shared__ __align__(16) float h2[2][H_];   // double-buffered swizzled h

    const int tid = threadIdx.x;
    const int b   = blockIdx.x;
    const int jg  = tid >> 2;      // hidden unit 0..127
    const int ks  = tid & 3;       // k-slice 0..3 (32 cols each)

    v2f Wr[16], Wz[16], Wn[16];
    {
        const v4f* wr = (const v4f*)(Whh + (size_t)(jg      ) * H_ + ks * 32);
        const v4f* wz = (const v4f*)(Whh + (size_t)(jg + 128) * H_ + ks * 32);
        const v4f* wn = (const v4f*)(Whh + (size_t)(jg + 256) * H_ + ks * 32);
#pragma unroll
        for (int c = 0; c < 8; c++) {
            v4f t;
            t = wr[c] * LOG2E_F;  Wr[2 * c] = t.lo; Wr[2 * c + 1] = t.hi;
            t = wz[c] * LOG2E_F;  Wz[2 * c] = t.lo; Wz[2 * c + 1] = t.hi;
            t = wn[c] * LOG2E2_F; Wn[2 * c] = t.lo; Wn[2 * c + 1] = t.hi;
        }
    }

    const float bhn = bhh[jg + 2 * H_] * LOG2E2_F;  // r,z biases folded into gx

    const float* gxb = gx + (size_t)b * T_ * G3_;
    float gr = gxb[jg], gz = gxb[jg + 128], gn = gxb[jg + 256];
    float h_old = 0.0f;

    if (tid < H_) h2[0][tid] = 0.0f;

    const int hw = ((jg >> 2) & 7) * 16 + (jg >> 5) * 4 + (jg & 3);
    const int hb = ks * 4;

    const float* gnx = gxb + G3_;
    float* hp = STORE_H ? (hseq + (size_t)b * T_ * H_ + jg) : nullptr;

    __syncthreads();

#define GRU_STEP(HIN, HOUT)                                                   \
    {                                                                         \
        const float gr2_ = gnx[jg];                                           \
        const float gz2_ = gnx[jg + 128];                                     \
        const float gn2_ = gnx[jg + 256];                                     \
        gnx += G3_;                                                           \
        v2f pr = {0.f, 0.f}, pz = {0.f, 0.f}, pn = {0.f, 0.f};                \
        _Pragma("unroll")                                                     \
        for (int c = 0; c < 8; c++) {                                         \
            v4f hv = *(const v4f*)&(HIN)[16 * c + hb];                        \
            v2f hlo = hv.lo, hhi = hv.hi;                                     \
            pk_fma(pr, hlo, Wr[2 * c]);  pk_fma(pr, hhi, Wr[2 * c + 1]);      \
            pk_fma(pz, hlo, Wz[2 * c]);  pk_fma(pz, hhi, Wz[2 * c + 1]);      \
            pk_fma(pn, hlo, Wn[2 * c]);  pk_fma(pn, hhi, Wn[2 * c + 1]);      \
        }                                                                     \
        const float p0 = bfly_fold4(pr.x + pr.y);                             \
        const float p1 = bfly_fold4(pz.x + pz.y);                             \
        const float p2 = bfly_fold4(pn.x + pn.y);                             \
        const float r_ = fast_rcp(1.0f + exp2_raw(-(gr + p0)));               \
        const float z_ = fast_rcp(1.0f + exp2_raw(-(gz + p1)));               \
        const float n_ = fmaf(-2.0f,                                          \
            fast_rcp(exp2_raw(gn + r_ * (p2 + bhn)) + 1.0f), 1.0f);           \
        h_old = fmaf(z_, h_old - n_, n_);                                     \
        if (ks == 0) {                                                        \
            (HOUT)[hw] = h_old;                                               \
            if (STORE_H) *hp = h_old;                                         \
        }                                                                     \
        if (STORE_H) hp += H_;                                                \
        gr = gr2_; gz = gz2_; gn = gn2_;                                      \
        lds_barrier();                                                        \
    }

    for (int t = 0; t < T_; t += 2) {
        GRU_STEP(h2[0], h2[1])
        GRU_STEP(h2[1], h2[0])
    }
#undef GRU_STEP

    if (FINAL) {
        if (ks == 0) h2[1][jg] = fmaxf(h_old, 0.0f);
        __syncthreads();
        if (tid < 3) {
            float acc = fc_b[tid];
            const float* fw = fc_w + tid * H_;
#pragma unroll
            for (int k = 0; k < H_; k++) acc = fmaf(h2[1][k], fw[k], acc);
            out[b * 3 + tid] = acc;
        }
    }
}

// ---------------------------------------------------------------------------
extern "C" void kernel_launch(void* const* d_in, const int* in_sizes, int n_in,
                              void* d_out, int out_size, void* d_ws, size_t ws_size,
                              hipStream_t stream)
{
    const int*   x    = (const int*)  d_in[0];
    const float* emb  = (const float*)d_in[1];
    const float* W_ih = (const float*)d_in[2];  // [2,384,128]
    const float* W_hh = (const float*)d_in[3];  // [2,384,128]
    const float* b_ih = (const float*)d_in[4];  // [2,384]
    const float* b_hh = (const float*)d_in[5];  // [2,384]
    const float* fc_w = (const float*)d_in[6];  // [3,128]
    const float* fc_b = (const float*)d_in[7];  // [3]
    float* out = (float*)d_out;

    const int M = B_ * T_;                                   // 131072 rows
    const size_t gx_f32 = (size_t)M * G3_ * sizeof(float);   // 201.3 MB

    float* gx = (float*)d_ws;
    float* h1 = (float*)((char*)d_ws + gx_f32);              // 67.1 MB

    dim3 ggx(G3_ / TN, M / TM);   // (3, 1024)
    dim3 bgx(256);
    dim3 grec(B_), brec(512);

    hipLaunchKernelGGL((gx_gemm<true>), ggx, bgx, 0, stream,
                       nullptr, x, emb, W_ih, b_ih, b_hh, gx);
    hipLaunchKernelGGL((gru_rec<true, false>), grec, brec, 0, stream,
                       gx, W_hh, b_hh, h1, nullptr, nullptr, nullptr);
    hipLaunchKernelGGL((gx_gemm<false>), ggx, bgx, 0, stream,
                       h1, nullptr, nullptr, W_ih + G3_ * H_, b_ih + G3_,
                       b_hh + G3_, gx);
    hipLaunchKernelGGL((gru_rec<false, true>), grec, brec, 0, stream,
                       gx, W_hh + G3_ * H_, b_hh + G3_, nullptr, fc_w, fc_b, out);
}

// Round 15
// 843.324 us; speedup vs baseline: 1.1275x; 1.0461x over previous
//
#include <hip/hip_runtime.h>
#include <hip/hip_bf16.h>

#define B_   256
#define T_   512
#define H_   128
#define G3_  384

// ---- tiled GEMM config ----
#define TM   128
#define TN   128
#define TK   32
#define LDA  132

// log2(e) and 2*log2(e): gate pre-activations are pre-scaled so the serial
// recurrence uses raw v_exp_f32 (2^x) with no per-call *1.4427 mul.
#define LOG2E_F  1.4426950408889634f
#define LOG2E2_F 2.8853900817779268f

typedef float v4f __attribute__((ext_vector_type(4)));
typedef float v2f __attribute__((ext_vector_type(2)));

__device__ __forceinline__ float fast_rcp(float x) {
    return __builtin_amdgcn_rcpf(x);
}
__device__ __forceinline__ float exp2_raw(float x) {
    return __builtin_amdgcn_exp2f(x);   // v_exp_f32: 2^x
}

// Packed FMA (R15-proven best dot form; half-rate but schedules best).
__device__ __forceinline__ void pk_fma(v2f& acc, v2f a, v2f b) {
    asm("v_pk_fma_f32 %0, %1, %2, %0" : "+v"(acc) : "v"(a), "v"(b));
}

// Butterfly sum over each aligned 4-lane quad, pure DPP, result on ALL lanes.
__device__ __forceinline__ float bfly_fold4(float v) {
    int x;
    x = __builtin_amdgcn_update_dpp(0, __float_as_int(v), 0x0B1, 0xF, 0xF, true);
    v += __int_as_float(x);   // xor 1
    x = __builtin_amdgcn_update_dpp(0, __float_as_int(v), 0x04E, 0xF, 0xF, true);
    v += __int_as_float(x);   // xor 2
    return v;
}

// R19 relaxed barrier (measured equal to __syncthreads, absmax 0).
__device__ __forceinline__ void lds_barrier() {
    asm volatile("s_waitcnt lgkmcnt(0)" ::: "memory");
    __builtin_amdgcn_s_barrier();
    asm volatile("" ::: "memory");
}

// ---------------------------------------------------------------------------
// gx GEMM (R2 structure; R14 bias2 fold; R15 exp2 pre-scale epilogue).
// R22: used ONCE (layer 1 only; layer-2's gx is produced inside gru_fused).
// ---------------------------------------------------------------------------
template<bool GATHER>
__global__ __launch_bounds__(256, 2)
void gx_gemm(const float* __restrict__ X,
             const int*   __restrict__ idx,
             const float* __restrict__ emb,
             const float* __restrict__ W,     // [384,128] row-major
             const float* __restrict__ bias,  // [384]  (b_ih)
             const float* __restrict__ bias2, // [384]  (b_hh; only n<256 used)
             float*       __restrict__ gx)    // [M,384]
{
    __shared__ __align__(16) float As[2][TK][LDA];
    __shared__ __align__(16) float Bs[2][TK][LDA];

    const int tid = threadIdx.x;
    const int tn  = tid & 15;
    const int tm  = tid >> 4;
    const int n0  = blockIdx.x * TN;
    const int m0  = blockIdx.y * TM;

    const int q  = tid & 7;
    const float* rowA[4];
    const float* rowB[4];
#pragma unroll
    for (int s = 0; s < 4; s++) {
        const int r = (tid >> 3) + 32 * s;
        rowA[s] = GATHER ? (emb + (size_t)idx[m0 + r] * H_)
                         : (X + (size_t)(m0 + r) * H_);
        rowB[s] = W + (size_t)(n0 + r) * H_;
    }

    float4 stA[4], stB[4];
    auto load_chunk = [&](int kc) {
#pragma unroll
        for (int s = 0; s < 4; s++) {
            stA[s] = *(const float4*)(rowA[s] + kc + q * 4);
            stB[s] = *(const float4*)(rowB[s] + kc + q * 4);
        }
    };
    auto store_chunk = [&](int buf) {
#pragma unroll
        for (int s = 0; s < 4; s++) {
            const int r = (tid >> 3) + 32 * s;
#pragma unroll
            for (int d = 0; d < 4; d++) {
                As[buf][q * 4 + d][r] = ((const float*)&stA[s])[d];
                Bs[buf][q * 4 + d][r] = ((const float*)&stB[s])[d];
            }
        }
    };

    float4 acc[2][2][4];
#pragma unroll
    for (int a = 0; a < 2; a++)
#pragma unroll
        for (int b = 0; b < 2; b++)
#pragma unroll
            for (int c = 0; c < 4; c++) acc[a][b][c] = make_float4(0.f, 0.f, 0.f, 0.f);

    load_chunk(0);
    store_chunk(0);
    __syncthreads();

    for (int c = 0; c < 4; c++) {
        if (c < 3) load_chunk((c + 1) * TK);
        const int buf = c & 1;
#pragma unroll 4
        for (int k = 0; k < TK; k++) {
            float4 a0 = *(const float4*)&As[buf][k][tm * 4];
            float4 a1 = *(const float4*)&As[buf][k][64 + tm * 4];
            float4 b0 = *(const float4*)&Bs[buf][k][tn * 4];
            float4 b1 = *(const float4*)&Bs[buf][k][64 + tn * 4];
            float4 av[2] = {a0, a1}, bv[2] = {b0, b1};
#pragma unroll
            for (int mg = 0; mg < 2; mg++)
#pragma unroll
                for (int mi = 0; mi < 4; mi++) {
                    const float am = ((const float*)&av[mg])[mi];
#pragma unroll
                    for (int ng = 0; ng < 2; ng++) {
                        acc[mg][ng][mi].x = fmaf(am, bv[ng].x, acc[mg][ng][mi].x);
                        acc[mg][ng][mi].y = fmaf(am, bv[ng].y, acc[mg][ng][mi].y);
                        acc[mg][ng][mi].z = fmaf(am, bv[ng].z, acc[mg][ng][mi].z);
                        acc[mg][ng][mi].w = fmaf(am, bv[ng].w, acc[mg][ng][mi].w);
                    }
                }
        }
        if (c < 3) {
            store_chunk(buf ^ 1);
            __syncthreads();
        }
    }

    float4 bb0 = *(const float4*)(bias + n0 + tn * 4);
    float4 bb1 = *(const float4*)(bias + n0 + 64 + tn * 4);
    if (n0 < 2 * H_) {   // r/z gate regions: fold hidden bias in here (uniform)
        const float4 c0 = *(const float4*)(bias2 + n0 + tn * 4);
        const float4 c1 = *(const float4*)(bias2 + n0 + 64 + tn * 4);
        bb0.x += c0.x; bb0.y += c0.y; bb0.z += c0.z; bb0.w += c0.w;
        bb1.x += c1.x; bb1.y += c1.y; bb1.z += c1.z; bb1.w += c1.w;
    }
    // exp2 pre-scale (uniform per block: r,z -> log2e; n -> 2log2e)
    const float esc = (n0 < 2 * H_) ? LOG2E_F : LOG2E2_F;
#pragma unroll
    for (int mg = 0; mg < 2; mg++)
#pragma unroll
        for (int mi = 0; mi < 4; mi++) {
            const int m = m0 + mg * 64 + tm * 4 + mi;
            float* dst = gx + (size_t)m * G3_ + n0;
            float4 v0 = acc[mg][0][mi];
            v0.x = (v0.x + bb0.x) * esc; v0.y = (v0.y + bb0.y) * esc;
            v0.z = (v0.z + bb0.z) * esc; v0.w = (v0.w + bb0.w) * esc;
            float4 v1 = acc[mg][1][mi];
            v1.x = (v1.x + bb1.x) * esc; v1.y = (v1.y + bb1.y) * esc;
            v1.z = (v1.z + bb1.z) * esc; v1.w = (v1.w + bb1.w) * esc;
            *(float4*)(dst + tn * 4) = v0;
            *(float4*)(dst + 64 + tn * 4) = v1;
        }
}

// ---------------------------------------------------------------------------
// R22: FUSED layer-1 recurrence + layer-2 gx GEMM.
//
// The R21 ledger: step = 708 cyc issue + ~575 cyc serial latency the 2
// lockstep waves cannot hide. This kernel fills that stall with INDEPENDENT
// work: the same hv = h[t-1] LDS reads also feed a second dot against
// W_ih2 rows {jg,jg+128,jg+256}, producing gx2[t-1] = gemm2's output row
// (bias-folded + exp2-prescaled). gemm2 (~140us) and the hseq store vanish.
//
// In-place gx overwrite is safe: row t-1's last READ is the prefetch at
// step t-2; its WRITE happens at step t (2 steps later, same lockstep
// block, own batch rows only). The final prefetch reads batch b+1 row 0
// (possibly already overwritten) but that value is never consumed.
// Epilogue computes row 511 from the final h. Write lanes: fold4 leaves
// the sum on ALL 4 lanes, so ks=1/2/3 write r/z/n while ks=0 writes h2.
// ---------------------------------------------------------------------------
__global__ __launch_bounds__(512)
__attribute__((amdgpu_waves_per_eu(2, 2)))
void gru_fused(float*       __restrict__ gx,    // [B,T,384] layer-1 in / layer-2 out
               const float* __restrict__ Whh,   // layer-1 [384,128]
               const float* __restrict__ bhh,   // layer-1 [384]
               const float* __restrict__ Wih2,  // layer-2 [384,128]
               const float* __restrict__ bih2,  // layer-2 [384]
               const float* __restrict__ bhh2)  // layer-2 [384]
{
    __shared__ __align__(16) float h2[2][H_];   // double-buffered swizzled h

    const int tid = threadIdx.x;
    const int b   = blockIdx.x;
    const int jg  = tid >> 2;      // hidden unit 0..127
    const int ks  = tid & 3;       // k-slice 0..3 (32 cols each)

    // --- layer-1 W_hh fragment (prescaled) ---
    v2f Wr[16], Wz[16], Wn[16];
    // --- layer-2 W_ih fragment (prescaled identically: r,z LOG2E; n LOG2E2) ---
    v2f Ar[16], Az[16], An[16];
    {
        const v4f* wr = (const v4f*)(Whh + (size_t)(jg      ) * H_ + ks * 32);
        const v4f* wz = (const v4f*)(Whh + (size_t)(jg + 128) * H_ + ks * 32);
        const v4f* wn = (const v4f*)(Whh + (size_t)(jg + 256) * H_ + ks * 32);
        const v4f* ar = (const v4f*)(Wih2 + (size_t)(jg      ) * H_ + ks * 32);
        const v4f* az = (const v4f*)(Wih2 + (size_t)(jg + 128) * H_ + ks * 32);
        const v4f* an = (const v4f*)(Wih2 + (size_t)(jg + 256) * H_ + ks * 32);
#pragma unroll
        for (int c = 0; c < 8; c++) {
            v4f t;
            t = wr[c] * LOG2E_F;  Wr[2 * c] = t.lo; Wr[2 * c + 1] = t.hi;
            t = wz[c] * LOG2E_F;  Wz[2 * c] = t.lo; Wz[2 * c + 1] = t.hi;
            t = wn[c] * LOG2E2_F; Wn[2 * c] = t.lo; Wn[2 * c + 1] = t.hi;
            t = ar[c] * LOG2E_F;  Ar[2 * c] = t.lo; Ar[2 * c + 1] = t.hi;
            t = az[c] * LOG2E_F;  Az[2 * c] = t.lo; Az[2 * c + 1] = t.hi;
            t = an[c] * LOG2E2_F; An[2 * c] = t.lo; An[2 * c + 1] = t.hi;
        }
    }

    const float bhn = bhh[jg + 2 * H_] * LOG2E2_F;  // layer-1 n hidden bias
    // layer-2 gx biases (b_ih2 + b_hh2 for r/z; b_ih2 only for n), prescaled
    const float br2 = (bih2[jg]           + bhh2[jg])           * LOG2E_F;
    const float bz2 = (bih2[jg + H_]      + bhh2[jg + H_])      * LOG2E_F;
    const float bn2 =  bih2[jg + 2 * H_]                        * LOG2E2_F;

    float* gxb = gx + (size_t)b * T_ * G3_;
    float gr = gxb[jg], gz = gxb[jg + 128], gn = gxb[jg + 256];
    float h_old = 0.0f;

    if (tid < H_) h2[0][tid] = 0.0f;

    const int hw = ((jg >> 2) & 7) * 16 + (jg >> 5) * 4 + (jg & 3);
    const int hb = ks * 4;
    const int woff = jg + (ks - 1) * H_;   // gx2 write offset for ks=1,2,3

    const float* gnx = gxb + G3_;          // prefetch walker (row t+1)
    float* gxw = gxb - G3_;                // gx2 write walker (row t-1)

    __syncthreads();

#define GRU_STEPF(HIN, HOUT, TT)                                              \
    {                                                                         \
        const float gr2_ = gnx[jg];                                           \
        const float gz2_ = gnx[jg + 128];                                     \
        const float gn2_ = gnx[jg + 256];                                     \
        gnx += G3_;                                                           \
        v2f pr = {0.f, 0.f}, pz = {0.f, 0.f}, pn = {0.f, 0.f};                \
        v2f qr = {0.f, 0.f}, qz = {0.f, 0.f}, qn = {0.f, 0.f};                \
        _Pragma("unroll")                                                     \
        for (int c = 0; c < 8; c++) {                                         \
            v4f hv = *(const v4f*)&(HIN)[16 * c + hb];                        \
            v2f hlo = hv.lo, hhi = hv.hi;                                     \
            pk_fma(pr, hlo, Wr[2 * c]);  pk_fma(pr, hhi, Wr[2 * c + 1]);      \
            pk_fma(pz, hlo, Wz[2 * c]);  pk_fma(pz, hhi, Wz[2 * c + 1]);      \
            pk_fma(pn, hlo, Wn[2 * c]);  pk_fma(pn, hhi, Wn[2 * c + 1]);      \
            pk_fma(qr, hlo, Ar[2 * c]);  pk_fma(qr, hhi, Ar[2 * c + 1]);      \
            pk_fma(qz, hlo, Az[2 * c]);  pk_fma(qz, hhi, Az[2 * c + 1]);      \
            pk_fma(qn, hlo, An[2 * c]);  pk_fma(qn, hhi, An[2 * c + 1]);      \
        }                                                                     \
        const float p0 = bfly_fold4(pr.x + pr.y);                             \
        const float p1 = bfly_fold4(pz.x + pz.y);                             \
        const float p2 = bfly_fold4(pn.x + pn.y);                             \
        const float q0 = bfly_fold4(qr.x + qr.y) + br2;                       \
        const float q1 = bfly_fold4(qz.x + qz.y) + bz2;                       \
        const float q2 = bfly_fold4(qn.x + qn.y) + bn2;                       \
        /* layer-2 gx row t-1 (valid for t>0): lanes ks=1,2,3 write r,z,n */  \
        if ((TT) > 0 && ks != 0) {                                            \
            gxw[woff] = (ks == 1) ? q0 : ((ks == 2) ? q1 : q2);               \
        }                                                                     \
        gxw += G3_;                                                           \
        const float r_ = fast_rcp(1.0f + exp2_raw(-(gr + p0)));               \
        const float z_ = fast_rcp(1.0f + exp2_raw(-(gz + p1)));               \
        const float n_ = fmaf(-2.0f,                                          \
            fast_rcp(exp2_raw(gn + r_ * (p2 + bhn)) + 1.0f), 1.0f);           \
        h_old = fmaf(z_, h_old - n_, n_);                                     \
        if (ks == 0) (HOUT)[hw] = h_old;                                      \
        gr = gr2_; gz = gz2_; gn = gn2_;                                      \
        lds_barrier();                                                        \
    }

    for (int t = 0; t < T_; t += 2) {
        GRU_STEPF(h2[0], h2[1], t)
        GRU_STEPF(h2[1], h2[0], t + 1)
    }
#undef GRU_STEPF

    // epilogue: gx2 row 511 from h[511] (in h2[0]; visible via final barrier)
    {
        v2f qr = {0.f, 0.f}, qz = {0.f, 0.f}, qn = {0.f, 0.f};
#pragma unroll
        for (int c = 0; c < 8; c++) {
            v4f hv = *(const v4f*)&h2[0][16 * c + hb];
            v2f hlo = hv.lo, hhi = hv.hi;
            pk_fma(qr, hlo, Ar[2 * c]);  pk_fma(qr, hhi, Ar[2 * c + 1]);
            pk_fma(qz, hlo, Az[2 * c]);  pk_fma(qz, hhi, Az[2 * c + 1]);
            pk_fma(qn, hlo, An[2 * c]);  pk_fma(qn, hhi, An[2 * c + 1]);
        }
        const float q0 = bfly_fold4(qr.x + qr.y) + br2;
        const float q1 = bfly_fold4(qz.x + qz.y) + bz2;
        const float q2 = bfly_fold4(qn.x + qn.y) + bn2;
        if (ks != 0) {
            gxw[woff] = (ks == 1) ? q0 : ((ks == 2) ? q1 : q2);
        }
    }
}

// ---------------------------------------------------------------------------
// GRU recurrence K=4 — R15/R21 kernel (layer 2, FINAL path).
// ---------------------------------------------------------------------------
template<bool STORE_H, bool FINAL>
__global__ __launch_bounds__(512)
__attribute__((amdgpu_waves_per_eu(2, 2)))
void gru_rec(const float* __restrict__ gx,   // [B,T,384] pre-scaled, r/z incl b_hh
             const float* __restrict__ Whh,  // [384,128]
             const float* __restrict__ bhh,  // [384]
             float*       __restrict__ hseq, // [B,T,128] if STORE_H
             const float* __restrict__ fc_w, // [3,128]  if FINAL
             const float* __restrict__ fc_b, // [3]      if FINAL
             float*       __restrict__ out)  // [B,3]    if FINAL
{
    __shared__ __align__(16) float h2[2][H_];   // double-buffered swizzled h

    const int tid = threadIdx.x;
    const int b   = blockIdx.x;
    const int jg  = tid >> 2;      // hidden unit 0..127
    const int ks  = tid & 3;       // k-slice 0..3 (32 cols each)

    v2f Wr[16], Wz[16], Wn[16];
    {
        const v4f* wr = (const v4f*)(Whh + (size_t)(jg      ) * H_ + ks * 32);
        const v4f* wz = (const v4f*)(Whh + (size_t)(jg + 128) * H_ + ks * 32);
        const v4f* wn = (const v4f*)(Whh + (size_t)(jg + 256) * H_ + ks * 32);
#pragma unroll
        for (int c = 0; c < 8; c++) {
            v4f t;
            t = wr[c] * LOG2E_F;  Wr[2 * c] = t.lo; Wr[2 * c + 1] = t.hi;
            t = wz[c] * LOG2E_F;  Wz[2 * c] = t.lo; Wz[2 * c + 1] = t.hi;
            t = wn[c] * LOG2E2_F; Wn[2 * c] = t.lo; Wn[2 * c + 1] = t.hi;
        }
    }

    const float bhn = bhh[jg + 2 * H_] * LOG2E2_F;

    const float* gxb = gx + (size_t)b * T_ * G3_;
    float gr = gxb[jg], gz = gxb[jg + 128], gn = gxb[jg + 256];
    float h_old = 0.0f;

    if (tid < H_) h2[0][tid] = 0.0f;

    const int hw = ((jg >> 2) & 7) * 16 + (jg >> 5) * 4 + (jg & 3);
    const int hb = ks * 4;

    const float* gnx = gxb + G3_;
    float* hp = STORE_H ? (hseq + (size_t)b * T_ * H_ + jg) : nullptr;

    __syncthreads();

#define GRU_STEP(HIN, HOUT)                                                   \
    {                                                                         \
        const float gr2_ = gnx[jg];                                           \
        const float gz2_ = gnx[jg + 128];                                     \
        const float gn2_ = gnx[jg + 256];                                     \
        gnx += G3_;                                                           \
        v2f pr = {0.f, 0.f}, pz = {0.f, 0.f}, pn = {0.f, 0.f};                \
        _Pragma("unroll")                                                     \
        for (int c = 0; c < 8; c++) {                                         \
            v4f hv = *(const v4f*)&(HIN)[16 * c + hb];                        \
            v2f hlo = hv.lo, hhi = hv.hi;                                     \
            pk_fma(pr, hlo, Wr[2 * c]);  pk_fma(pr, hhi, Wr[2 * c + 1]);      \
            pk_fma(pz, hlo, Wz[2 * c]);  pk_fma(pz, hhi, Wz[2 * c + 1]);      \
            pk_fma(pn, hlo, Wn[2 * c]);  pk_fma(pn, hhi, Wn[2 * c + 1]);      \
        }                                                                     \
        const float p0 = bfly_fold4(pr.x + pr.y);                             \
        const float p1 = bfly_fold4(pz.x + pz.y);                             \
        const float p2 = bfly_fold4(pn.x + pn.y);                             \
        const float r_ = fast_rcp(1.0f + exp2_raw(-(gr + p0)));               \
        const float z_ = fast_rcp(1.0f + exp2_raw(-(gz + p1)));               \
        const float n_ = fmaf(-2.0f,                                          \
            fast_rcp(exp2_raw(gn + r_ * (p2 + bhn)) + 1.0f), 1.0f);           \
        h_old = fmaf(z_, h_old - n_, n_);                                     \
        if (ks == 0) {                                                        \
            (HOUT)[hw] = h_old;                                               \
            if (STORE_H) *hp = h_old;                                         \
        }                                                                     \
        if (STORE_H) hp += H_;                                                \
        gr = gr2_; gz = gz2_; gn = gn2_;                                      \
        lds_barrier();                                                        \
    }

    for (int t = 0; t < T_; t += 2) {
        GRU_STEP(h2[0], h2[1])
        GRU_STEP(h2[1], h2[0])
    }
#undef GRU_STEP

    if (FINAL) {
        if (ks == 0) h2[1][jg] = fmaxf(h_old, 0.0f);
        __syncthreads();
        if (tid < 3) {
            float acc = fc_b[tid];
            const float* fw = fc_w + tid * H_;
#pragma unroll
            for (int k = 0; k < H_; k++) acc = fmaf(h2[1][k], fw[k], acc);
            out[b * 3 + tid] = acc;
        }
    }
}

// ---------------------------------------------------------------------------
extern "C" void kernel_launch(void* const* d_in, const int* in_sizes, int n_in,
                              void* d_out, int out_size, void* d_ws, size_t ws_size,
                              hipStream_t stream)
{
    const int*   x    = (const int*)  d_in[0];
    const float* emb  = (const float*)d_in[1];
    const float* W_ih = (const float*)d_in[2];  // [2,384,128]
    const float* W_hh = (const float*)d_in[3];  // [2,384,128]
    const float* b_ih = (const float*)d_in[4];  // [2,384]
    const float* b_hh = (const float*)d_in[5];  // [2,384]
    const float* fc_w = (const float*)d_in[6];  // [3,128]
    const float* fc_b = (const float*)d_in[7];  // [3]
    float* out = (float*)d_out;

    const int M = B_ * T_;                                   // 131072 rows

    float* gx = (float*)d_ws;                                // 201.3 MB

    dim3 ggx(G3_ / TN, M / TM);   // (3, 1024)
    dim3 bgx(256);
    dim3 grec(B_), brec(512);

    // layer-1 gx from embeddings (bias-folded, prescaled)
    hipLaunchKernelGGL((gx_gemm<true>), ggx, bgx, 0, stream,
                       nullptr, x, emb, W_ih, b_ih, b_hh, gx);
    // fused: layer-1 recurrence + layer-2 gx GEMM (in-place into gx)
    hipLaunchKernelGGL(gru_fused, grec, brec, 0, stream,
                       gx, W_hh, b_hh,
                       W_ih + G3_ * H_, b_ih + G3_, b_hh + G3_);
    // layer-2 recurrence + relu + FC
    hipLaunchKernelGGL((gru_rec<false, true>), grec, brec, 0, stream,
                       gx, W_hh + G3_ * H_, b_hh + G3_, nullptr, fc_w, fc_b, out);
}

// Round 16
// 836.094 us; speedup vs baseline: 1.1373x; 1.0086x over previous
//
#include <hip/hip_runtime.h>
#include <hip/hip_bf16.h>

#define B_   256
#define T_   512
#define H_   128
#define G3_  384

// ---- tiled GEMM config ----
#define TM   128
#define TN   128
#define TK   32
#define LDA  132

// log2(e) and 2*log2(e): gate pre-activations are pre-scaled so the serial
// recurrence uses raw v_exp_f32 (2^x) with no per-call *1.4427 mul.
#define LOG2E_F  1.4426950408889634f
#define LOG2E2_F 2.8853900817779268f

typedef float v4f __attribute__((ext_vector_type(4)));
typedef float v2f __attribute__((ext_vector_type(2)));

__device__ __forceinline__ float fast_rcp(float x) {
    return __builtin_amdgcn_rcpf(x);
}
__device__ __forceinline__ float exp2_raw(float x) {
    return __builtin_amdgcn_exp2f(x);   // v_exp_f32: 2^x
}

// Packed FMA (R15-proven best dot form; half-rate but schedules best).
__device__ __forceinline__ void pk_fma(v2f& acc, v2f a, v2f b) {
    asm("v_pk_fma_f32 %0, %1, %2, %0" : "+v"(acc) : "v"(a), "v"(b));
}

// Butterfly sum over each aligned 4-lane quad, pure DPP, result on ALL lanes.
__device__ __forceinline__ float bfly_fold4(float v) {
    int x;
    x = __builtin_amdgcn_update_dpp(0, __float_as_int(v), 0x0B1, 0xF, 0xF, true);
    v += __int_as_float(x);   // xor 1
    x = __builtin_amdgcn_update_dpp(0, __float_as_int(v), 0x04E, 0xF, 0xF, true);
    v += __int_as_float(x);   // xor 2
    return v;
}

// R19 relaxed barrier (measured equal to __syncthreads, absmax 0).
__device__ __forceinline__ void lds_barrier() {
    asm volatile("s_waitcnt lgkmcnt(0)" ::: "memory");
    __builtin_amdgcn_s_barrier();
    asm volatile("" ::: "memory");
}

// ---------------------------------------------------------------------------
// gx GEMM (R2 structure; R14 bias2 fold; R15 exp2 pre-scale epilogue).
// Used once: layer-1 gx from embeddings.
// ---------------------------------------------------------------------------
template<bool GATHER>
__global__ __launch_bounds__(256, 2)
void gx_gemm(const float* __restrict__ X,
             const int*   __restrict__ idx,
             const float* __restrict__ emb,
             const float* __restrict__ W,     // [384,128] row-major
             const float* __restrict__ bias,  // [384]  (b_ih)
             const float* __restrict__ bias2, // [384]  (b_hh; only n<256 used)
             float*       __restrict__ gx)    // [M,384]
{
    __shared__ __align__(16) float As[2][TK][LDA];
    __shared__ __align__(16) float Bs[2][TK][LDA];

    const int tid = threadIdx.x;
    const int tn  = tid & 15;
    const int tm  = tid >> 4;
    const int n0  = blockIdx.x * TN;
    const int m0  = blockIdx.y * TM;

    const int q  = tid & 7;
    const float* rowA[4];
    const float* rowB[4];
#pragma unroll
    for (int s = 0; s < 4; s++) {
        const int r = (tid >> 3) + 32 * s;
        rowA[s] = GATHER ? (emb + (size_t)idx[m0 + r] * H_)
                         : (X + (size_t)(m0 + r) * H_);
        rowB[s] = W + (size_t)(n0 + r) * H_;
    }

    float4 stA[4], stB[4];
    auto load_chunk = [&](int kc) {
#pragma unroll
        for (int s = 0; s < 4; s++) {
            stA[s] = *(const float4*)(rowA[s] + kc + q * 4);
            stB[s] = *(const float4*)(rowB[s] + kc + q * 4);
        }
    };
    auto store_chunk = [&](int buf) {
#pragma unroll
        for (int s = 0; s < 4; s++) {
            const int r = (tid >> 3) + 32 * s;
#pragma unroll
            for (int d = 0; d < 4; d++) {
                As[buf][q * 4 + d][r] = ((const float*)&stA[s])[d];
                Bs[buf][q * 4 + d][r] = ((const float*)&stB[s])[d];
            }
        }
    };

    float4 acc[2][2][4];
#pragma unroll
    for (int a = 0; a < 2; a++)
#pragma unroll
        for (int b = 0; b < 2; b++)
#pragma unroll
            for (int c = 0; c < 4; c++) acc[a][b][c] = make_float4(0.f, 0.f, 0.f, 0.f);

    load_chunk(0);
    store_chunk(0);
    __syncthreads();

    for (int c = 0; c < 4; c++) {
        if (c < 3) load_chunk((c + 1) * TK);
        const int buf = c & 1;
#pragma unroll 4
        for (int k = 0; k < TK; k++) {
            float4 a0 = *(const float4*)&As[buf][k][tm * 4];
            float4 a1 = *(const float4*)&As[buf][k][64 + tm * 4];
            float4 b0 = *(const float4*)&Bs[buf][k][tn * 4];
            float4 b1 = *(const float4*)&Bs[buf][k][64 + tn * 4];
            float4 av[2] = {a0, a1}, bv[2] = {b0, b1};
#pragma unroll
            for (int mg = 0; mg < 2; mg++)
#pragma unroll
                for (int mi = 0; mi < 4; mi++) {
                    const float am = ((const float*)&av[mg])[mi];
#pragma unroll
                    for (int ng = 0; ng < 2; ng++) {
                        acc[mg][ng][mi].x = fmaf(am, bv[ng].x, acc[mg][ng][mi].x);
                        acc[mg][ng][mi].y = fmaf(am, bv[ng].y, acc[mg][ng][mi].y);
                        acc[mg][ng][mi].z = fmaf(am, bv[ng].z, acc[mg][ng][mi].z);
                        acc[mg][ng][mi].w = fmaf(am, bv[ng].w, acc[mg][ng][mi].w);
                    }
                }
        }
        if (c < 3) {
            store_chunk(buf ^ 1);
            __syncthreads();
        }
    }

    float4 bb0 = *(const float4*)(bias + n0 + tn * 4);
    float4 bb1 = *(const float4*)(bias + n0 + 64 + tn * 4);
    if (n0 < 2 * H_) {   // r/z gate regions: fold hidden bias in here (uniform)
        const float4 c0 = *(const float4*)(bias2 + n0 + tn * 4);
        const float4 c1 = *(const float4*)(bias2 + n0 + 64 + tn * 4);
        bb0.x += c0.x; bb0.y += c0.y; bb0.z += c0.z; bb0.w += c0.w;
        bb1.x += c1.x; bb1.y += c1.y; bb1.z += c1.z; bb1.w += c1.w;
    }
    // exp2 pre-scale (uniform per block: r,z -> log2e; n -> 2log2e)
    const float esc = (n0 < 2 * H_) ? LOG2E_F : LOG2E2_F;
#pragma unroll
    for (int mg = 0; mg < 2; mg++)
#pragma unroll
        for (int mi = 0; mi < 4; mi++) {
            const int m = m0 + mg * 64 + tm * 4 + mi;
            float* dst = gx + (size_t)m * G3_ + n0;
            float4 v0 = acc[mg][0][mi];
            v0.x = (v0.x + bb0.x) * esc; v0.y = (v0.y + bb0.y) * esc;
            v0.z = (v0.z + bb0.z) * esc; v0.w = (v0.w + bb0.w) * esc;
            float4 v1 = acc[mg][1][mi];
            v1.x = (v1.x + bb1.x) * esc; v1.y = (v1.y + bb1.y) * esc;
            v1.z = (v1.z + bb1.z) * esc; v1.w = (v1.w + bb1.w) * esc;
            *(float4*)(dst + tn * 4) = v0;
            *(float4*)(dst + 64 + tn * 4) = v1;
        }
}

// ---------------------------------------------------------------------------
// R23: fused layer-1 recurrence + layer-2 gx GEMM on SEPARATE WAVES.
//
// R22 post-mortem: in-stream fusion didn't absorb the 575-cyc stall (q-work
// extended the same serial chain; step 1284 -> 2130). R23 moves the q-work
// to dedicated helper waves with independent instruction streams:
//   waves 0-7  (tid < 512): exact R21 recurrence (354 cyc/wave issue).
//   waves 8-15 (tid >= 512): per step, read the SAME h[t-1] LDS buffer
//     (identical conflict-free addresses) and compute gx2 row t-1 =
//     h[t-1]·W_ih2 + bias (prescaled), in-place into gx. 48 pk_fma +
//     3 fold4 per thread, no gates.
// Wave->SIMD round-robin gives each SIMD 2 rec + 2 helper waves; helper
// issue (~520 cyc/SIMD) fills the rec stall window (~575 cyc). Both
// branches execute exactly T_ lds_barrier()s -> barrier counts match.
// Buffer lifetime: h2[buf] read at step t is overwritten at t+2; helpers
// finish reading before the step-t barrier. In-place gx write of row t-1
// is safe (last read was the rec prefetch at step t-2). Epilogue: helpers
// compute row 511 from h[511] (in h2[0] after the final barrier).
// VGPR: each branch needs ~96 W + ~30 live <= 128 budget (waves_per_eu 4).
// ---------------------------------------------------------------------------
__global__ __launch_bounds__(1024)
__attribute__((amdgpu_waves_per_eu(4, 4)))
void gru_fused(float*       __restrict__ gx,    // [B,T,384] layer-1 in / layer-2 out
               const float* __restrict__ Whh,   // layer-1 [384,128]
               const float* __restrict__ bhh,   // layer-1 [384]
               const float* __restrict__ Wih2,  // layer-2 [384,128]
               const float* __restrict__ bih2,  // layer-2 [384]
               const float* __restrict__ bhh2)  // layer-2 [384]
{
    __shared__ __align__(16) float h2[2][H_];   // double-buffered swizzled h

    const int tid = threadIdx.x;
    const int b   = blockIdx.x;
    float* gxb = gx + (size_t)b * T_ * G3_;

    if (tid < H_) h2[0][tid] = 0.0f;   // zeros are swizzle-invariant
    __syncthreads();

    if (tid < 512) {
        // =================== recurrence waves (R21 body) ===================
        const int jg = tid >> 2;      // hidden unit 0..127
        const int ks = tid & 3;       // k-slice 0..3 (32 cols each)

        v2f Wr[16], Wz[16], Wn[16];
        {
            const v4f* wr = (const v4f*)(Whh + (size_t)(jg      ) * H_ + ks * 32);
            const v4f* wz = (const v4f*)(Whh + (size_t)(jg + 128) * H_ + ks * 32);
            const v4f* wn = (const v4f*)(Whh + (size_t)(jg + 256) * H_ + ks * 32);
#pragma unroll
            for (int c = 0; c < 8; c++) {
                v4f t;
                t = wr[c] * LOG2E_F;  Wr[2 * c] = t.lo; Wr[2 * c + 1] = t.hi;
                t = wz[c] * LOG2E_F;  Wz[2 * c] = t.lo; Wz[2 * c + 1] = t.hi;
                t = wn[c] * LOG2E2_F; Wn[2 * c] = t.lo; Wn[2 * c + 1] = t.hi;
            }
        }

        const float bhn = bhh[jg + 2 * H_] * LOG2E2_F;
        float gr = gxb[jg], gz = gxb[jg + 128], gn = gxb[jg + 256];
        float h_old = 0.0f;

        const int hw = ((jg >> 2) & 7) * 16 + (jg >> 5) * 4 + (jg & 3);
        const int hb = ks * 4;
        const float* gnx = gxb + G3_;

#define REC_STEP(HIN, HOUT)                                                   \
        {                                                                     \
            const float gr2_ = gnx[jg];                                       \
            const float gz2_ = gnx[jg + 128];                                 \
            const float gn2_ = gnx[jg + 256];                                 \
            gnx += G3_;                                                       \
            v2f pr = {0.f, 0.f}, pz = {0.f, 0.f}, pn = {0.f, 0.f};            \
            _Pragma("unroll")                                                 \
            for (int c = 0; c < 8; c++) {                                     \
                v4f hv = *(const v4f*)&(HIN)[16 * c + hb];                    \
                v2f hlo = hv.lo, hhi = hv.hi;                                 \
                pk_fma(pr, hlo, Wr[2 * c]);  pk_fma(pr, hhi, Wr[2 * c + 1]);  \
                pk_fma(pz, hlo, Wz[2 * c]);  pk_fma(pz, hhi, Wz[2 * c + 1]);  \
                pk_fma(pn, hlo, Wn[2 * c]);  pk_fma(pn, hhi, Wn[2 * c + 1]);  \
            }                                                                 \
            const float p0 = bfly_fold4(pr.x + pr.y);                         \
            const float p1 = bfly_fold4(pz.x + pz.y);                         \
            const float p2 = bfly_fold4(pn.x + pn.y);                         \
            const float r_ = fast_rcp(1.0f + exp2_raw(-(gr + p0)));           \
            const float z_ = fast_rcp(1.0f + exp2_raw(-(gz + p1)));           \
            const float n_ = fmaf(-2.0f,                                      \
                fast_rcp(exp2_raw(gn + r_ * (p2 + bhn)) + 1.0f), 1.0f);       \
            h_old = fmaf(z_, h_old - n_, n_);                                 \
            if (ks == 0) (HOUT)[hw] = h_old;                                  \
            gr = gr2_; gz = gz2_; gn = gn2_;                                  \
            lds_barrier();                                                    \
        }

        for (int t = 0; t < T_; t += 2) {
            REC_STEP(h2[0], h2[1])
            REC_STEP(h2[1], h2[0])
        }
#undef REC_STEP
    } else {
        // ===================== helper waves (gemm2) ========================
        const int t2 = tid - 512;
        const int jq = t2 >> 2;       // output unit 0..127
        const int kq = t2 & 3;        // k-slice 0..3

        v2f Ar[16], Az[16], An[16];
        {
            const v4f* ar = (const v4f*)(Wih2 + (size_t)(jq      ) * H_ + kq * 32);
            const v4f* az = (const v4f*)(Wih2 + (size_t)(jq + 128) * H_ + kq * 32);
            const v4f* an = (const v4f*)(Wih2 + (size_t)(jq + 256) * H_ + kq * 32);
#pragma unroll
            for (int c = 0; c < 8; c++) {
                v4f t;
                t = ar[c] * LOG2E_F;  Ar[2 * c] = t.lo; Ar[2 * c + 1] = t.hi;
                t = az[c] * LOG2E_F;  Az[2 * c] = t.lo; Az[2 * c + 1] = t.hi;
                t = an[c] * LOG2E2_F; An[2 * c] = t.lo; An[2 * c + 1] = t.hi;
            }
        }

        const float br2 = (bih2[jq]          + bhh2[jq])          * LOG2E_F;
        const float bz2 = (bih2[jq + H_]     + bhh2[jq + H_])     * LOG2E_F;
        const float bn2 =  bih2[jq + 2 * H_]                      * LOG2E2_F;

        const int qb   = kq * 4;
        const int woff = jq + (kq - 1) * H_;   // write offset for kq=1,2,3
        float* gxw = gxb - G3_;                // row t-1 walker

#define Q_DOT(HIN)                                                            \
            v2f qr = {0.f, 0.f}, qz = {0.f, 0.f}, qn = {0.f, 0.f};            \
            _Pragma("unroll")                                                 \
            for (int c = 0; c < 8; c++) {                                     \
                v4f hv = *(const v4f*)&(HIN)[16 * c + qb];                    \
                v2f hlo = hv.lo, hhi = hv.hi;                                 \
                pk_fma(qr, hlo, Ar[2 * c]);  pk_fma(qr, hhi, Ar[2 * c + 1]);  \
                pk_fma(qz, hlo, Az[2 * c]);  pk_fma(qz, hhi, Az[2 * c + 1]);  \
                pk_fma(qn, hlo, An[2 * c]);  pk_fma(qn, hhi, An[2 * c + 1]);  \
            }                                                                 \
            const float q0 = bfly_fold4(qr.x + qr.y) + br2;                   \
            const float q1 = bfly_fold4(qz.x + qz.y) + bz2;                   \
            const float q2 = bfly_fold4(qn.x + qn.y) + bn2;

#define Q_STEP(HIN, TT)                                                       \
        {                                                                     \
            Q_DOT(HIN)                                                        \
            if ((TT) > 0 && kq != 0) {                                        \
                gxw[woff] = (kq == 1) ? q0 : ((kq == 2) ? q1 : q2);           \
            }                                                                 \
            gxw += G3_;                                                       \
            lds_barrier();                                                    \
        }

        for (int t = 0; t < T_; t += 2) {
            Q_STEP(h2[0], t)
            Q_STEP(h2[1], t + 1)
        }

        // epilogue: row 511 from h[511] (in h2[0], visible via final barrier)
        {
            Q_DOT(h2[0])
            if (kq != 0) {
                gxw[woff] = (kq == 1) ? q0 : ((kq == 2) ? q1 : q2);
            }
        }
#undef Q_STEP
#undef Q_DOT
    }
}

// ---------------------------------------------------------------------------
// GRU recurrence K=4 — R15/R21 kernel (layer 2, FINAL path).
// ---------------------------------------------------------------------------
template<bool STORE_H, bool FINAL>
__global__ __launch_bounds__(512)
__attribute__((amdgpu_waves_per_eu(2, 2)))
void gru_rec(const float* __restrict__ gx,   // [B,T,384] pre-scaled, r/z incl b_hh
             const float* __restrict__ Whh,  // [384,128]
             const float* __restrict__ bhh,  // [384]
             float*       __restrict__ hseq, // [B,T,128] if STORE_H
             const float* __restrict__ fc_w, // [3,128]  if FINAL
             const float* __restrict__ fc_b, // [3]      if FINAL
             float*       __restrict__ out)  // [B,3]    if FINAL
{
    __shared__ __align__(16) float h2[2][H_];   // double-buffered swizzled h

    const int tid = threadIdx.x;
    const int b   = blockIdx.x;
    const int jg  = tid >> 2;      // hidden unit 0..127
    const int ks  = tid & 3;       // k-slice 0..3 (32 cols each)

    v2f Wr[16], Wz[16], Wn[16];
    {
        const v4f* wr = (const v4f*)(Whh + (size_t)(jg      ) * H_ + ks * 32);
        const v4f* wz = (const v4f*)(Whh + (size_t)(jg + 128) * H_ + ks * 32);
        const v4f* wn = (const v4f*)(Whh + (size_t)(jg + 256) * H_ + ks * 32);
#pragma unroll
        for (int c = 0; c < 8; c++) {
            v4f t;
            t = wr[c] * LOG2E_F;  Wr[2 * c] = t.lo; Wr[2 * c + 1] = t.hi;
            t = wz[c] * LOG2E_F;  Wz[2 * c] = t.lo; Wz[2 * c + 1] = t.hi;
            t = wn[c] * LOG2E2_F; Wn[2 * c] = t.lo; Wn[2 * c + 1] = t.hi;
        }
    }

    const float bhn = bhh[jg + 2 * H_] * LOG2E2_F;

    const float* gxb = gx + (size_t)b * T_ * G3_;
    float gr = gxb[jg], gz = gxb[jg + 128], gn = gxb[jg + 256];
    float h_old = 0.0f;

    if (tid < H_) h2[0][tid] = 0.0f;

    const int hw = ((jg >> 2) & 7) * 16 + (jg >> 5) * 4 + (jg & 3);
    const int hb = ks * 4;

    const float* gnx = gxb + G3_;
    float* hp = STORE_H ? (hseq + (size_t)b * T_ * H_ + jg) : nullptr;

    __syncthreads();

#define GRU_STEP(HIN, HOUT)                                                   \
    {                                                                         \
        const float gr2_ = gnx[jg];                                           \
        const float gz2_ = gnx[jg + 128];                                     \
        const float gn2_ = gnx[jg + 256];                                     \
        gnx += G3_;                                                           \
        v2f pr = {0.f, 0.f}, pz = {0.f, 0.f}, pn = {0.f, 0.f};                \
        _Pragma("unroll")                                                     \
        for (int c = 0; c < 8; c++) {                                         \
            v4f hv = *(const v4f*)&(HIN)[16 * c + hb];                        \
            v2f hlo = hv.lo, hhi = hv.hi;                                     \
            pk_fma(pr, hlo, Wr[2 * c]);  pk_fma(pr, hhi, Wr[2 * c + 1]);      \
            pk_fma(pz, hlo, Wz[2 * c]);  pk_fma(pz, hhi, Wz[2 * c + 1]);      \
            pk_fma(pn, hlo, Wn[2 * c]);  pk_fma(pn, hhi, Wn[2 * c + 1]);      \
        }                                                                     \
        const float p0 = bfly_fold4(pr.x + pr.y);                             \
        const float p1 = bfly_fold4(pz.x + pz.y);                             \
        const float p2 = bfly_fold4(pn.x + pn.y);                             \
        const float r_ = fast_rcp(1.0f + exp2_raw(-(gr + p0)));               \
        const float z_ = fast_rcp(1.0f + exp2_raw(-(gz + p1)));               \
        const float n_ = fmaf(-2.0f,                                          \
            fast_rcp(exp2_raw(gn + r_ * (p2 + bhn)) + 1.0f), 1.0f);           \
        h_old = fmaf(z_, h_old - n_, n_);                                     \
        if (ks == 0) {                                                        \
            (HOUT)[hw] = h_old;                                               \
            if (STORE_H) *hp = h_old;                                         \
        }                                                                     \
        if (STORE_H) hp += H_;                                                \
        gr = gr2_; gz = gz2_; gn = gn2_;                                      \
        lds_barrier();                                                        \
    }

    for (int t = 0; t < T_; t += 2) {
        GRU_STEP(h2[0], h2[1])
        GRU_STEP(h2[1], h2[0])
    }
#undef GRU_STEP

    if (FINAL) {
        if (ks == 0) h2[1][jg] = fmaxf(h_old, 0.0f);
        __syncthreads();
        if (tid < 3) {
            float acc = fc_b[tid];
            const float* fw = fc_w + tid * H_;
#pragma unroll
            for (int k = 0; k < H_; k++) acc = fmaf(h2[1][k], fw[k], acc);
            out[b * 3 + tid] = acc;
        }
    }
}

// ---------------------------------------------------------------------------
extern "C" void kernel_launch(void* const* d_in, const int* in_sizes, int n_in,
                              void* d_out, int out_size, void* d_ws, size_t ws_size,
                              hipStream_t stream)
{
    const int*   x    = (const int*)  d_in[0];
    const float* emb  = (const float*)d_in[1];
    const float* W_ih = (const float*)d_in[2];  // [2,384,128]
    const float* W_hh = (const float*)d_in[3];  // [2,384,128]
    const float* b_ih = (const float*)d_in[4];  // [2,384]
    const float* b_hh = (const float*)d_in[5];  // [2,384]
    const float* fc_w = (const float*)d_in[6];  // [3,128]
    const float* fc_b = (const float*)d_in[7];  // [3]
    float* out = (float*)d_out;

    const int M = B_ * T_;                                   // 131072 rows

    float* gx = (float*)d_ws;                                // 201.3 MB

    dim3 ggx(G3_ / TN, M / TM);   // (3, 1024)
    dim3 bgx(256);
    dim3 grec(B_);

    // layer-1 gx from embeddings (bias-folded, prescaled)
    hipLaunchKernelGGL((gx_gemm<true>), ggx, bgx, 0, stream,
                       nullptr, x, emb, W_ih, b_ih, b_hh, gx);
    // fused: layer-1 recurrence (waves 0-7) + layer-2 gx GEMM (waves 8-15)
    hipLaunchKernelGGL(gru_fused, grec, dim3(1024), 0, stream,
                       gx, W_hh, b_hh,
                       W_ih + G3_ * H_, b_ih + G3_, b_hh + G3_);
    // layer-2 recurrence + relu + FC
    hipLaunchKernelGGL((gru_rec<false, true>), grec, dim3(512), 0, stream,
                       gx, W_hh + G3_ * H_, b_hh + G3_, nullptr, fc_w, fc_b, out);
}